// Round 12
// baseline (58.268 us; speedup 1.0000x reference)
//
#include <hip/hip_runtime.h>

typedef __attribute__((ext_vector_type(8))) short short8;
typedef __attribute__((ext_vector_type(8))) unsigned short ushort8;
typedef __attribute__((ext_vector_type(4))) unsigned short ushort4v;
typedef __attribute__((ext_vector_type(4))) int int4v;
typedef __attribute__((ext_vector_type(4))) float f32x4;

#define Mdim 64
#define Kdim 8192
#define Ndim 8192
#define GRP 128
#define NGRP 64
#define KSPLIT 4
#define NG2 (NGRP / KSPLIT)   // 16 groups per block
#define BN 128

// Swizzled element offset in a [row][128]-bf16 LDS tile (256 B rows).
#define SWZ(row, kk) ((row)*128 + ((kk) ^ (8*((((row) >> 3) ^ (row)) & 7))))

__device__ __forceinline__ unsigned short f2bf(float f) {
    unsigned int u = __builtin_bit_cast(unsigned int, f);
    u += 0x7FFFu + ((u >> 16) & 1u);   // round-to-nearest-even
    return (unsigned short)(u >> 16);
}
__device__ __forceinline__ float bf2f(unsigned short h) {
    unsigned int u = ((unsigned int)h) << 16;
    return __builtin_bit_cast(float, u);
}

// Build xh/xl (hi/lo bf16 split of x) and per-(group,m) sums xsum[g][m].
__global__ void prep_kernel(const float* __restrict__ x,
                            unsigned short* __restrict__ xh,
                            unsigned short* __restrict__ xl,
                            float* __restrict__ xsum) {
    const int tid = threadIdx.x;
    const int u = blockIdx.x * 8 + (tid >> 5);
    const int g = u & (NGRP - 1);
    const int m = u >> 6;
    const int lane = tid & 31;
    const int k = g * GRP + lane * 4;
    f32x4 v = *(const f32x4*)(x + (size_t)m * Kdim + k);
    ushort4v hv, lv;
    float s = 0.f;
#pragma unroll
    for (int i = 0; i < 4; ++i) {
        unsigned short h = f2bf(v[i]);
        hv[i] = h;
        lv[i] = f2bf(v[i] - bf2f(h));
        s += v[i];
    }
    *(ushort4v*)(xh + (size_t)m * Kdim + k) = hv;
    *(ushort4v*)(xl + (size_t)m * Kdim + k) = lv;
#pragma unroll
    for (int off = 16; off > 0; off >>= 1) s += __shfl_down(s, off, 32);
    if (lane == 0) xsum[g * Mdim + m] = s;
}

// out = bias (broadcast over rows); qlin atomically accumulates into it.
__global__ void init_kernel(const float* __restrict__ bias,
                            float* __restrict__ out) {
    const size_t e = ((size_t)blockIdx.x * 256 + threadIdx.x) * 4;
    const int n = (int)(e & (Ndim - 1));
    *(f32x4*)(out + e) = *(const f32x4*)(bias + n);
}

// q load: 8 rows x 16B per thread into a NAMED reg set (static indices only)
#define LOADQ_M(dst, g) do {                                                  \
    const size_t kb_ = (size_t)(g) * GRP + qr * 8;                            \
    const int nc_ = n0 + qc * 4;                                              \
    _Pragma("unroll")                                                         \
    for (int j = 0; j < 8; ++j)                                               \
        dst[j] = *(const int4v*)(qw + (kb_ + j) * Ndim + nc_);                \
} while (0)

// exact int->bf16 (|q|<=128 => truncation exact), b128 swizzled LDS writes
#define WRITEQ_M(src, b) do {                                                 \
    _Pragma("unroll")                                                         \
    for (int i = 0; i < 4; ++i) {                                             \
        int4v pk_;                                                            \
        _Pragma("unroll")                                                     \
        for (int t = 0; t < 4; ++t) {                                         \
            unsigned lo_ = __builtin_bit_cast(unsigned, (float)src[2*t][i]) >> 16;           \
            unsigned hi_ = __builtin_bit_cast(unsigned, (float)src[2*t+1][i]) & 0xFFFF0000u; \
            pk_[t] = (int)(lo_ | hi_);                                        \
        }                                                                     \
        *(int4v*)&lq[b][SWZ(qc * 4 + i, qr * 8)] = pk_;                       \
    }                                                                         \
} while (0)

// Main: 256 blocks = 64 n-tiles (BN=128) x KSPLIT=4, 1 block/CU (148 KB LDS).
// 512 threads = 8 waves = 2 m-tiles(32) x 4 n-strips(32).
// Counted-vmcnt pipeline, RAW barriers (vmem survives), and a 2-SLOT q
// delivery window: q(j) issued in slot j-3 via alternating reg sets qva/qvb,
// drained (WRITEQ) in slot j-1 -> ~11.7k cy for HBM delivery, straggler-proof.
// Epilogue: fp32 atomicAdd into bias-initialized out (no pout/reduce pass).
__launch_bounds__(512, 2)
__global__ void qlin_kernel(const unsigned short* __restrict__ xh,
                            const unsigned short* __restrict__ xl,
                            const int* __restrict__ qw,
                            const float* __restrict__ scales,
                            const float* __restrict__ zeros,
                            const float* __restrict__ xsum,
                            float* __restrict__ out) {
    __shared__ unsigned short lq[2][128 * 128];   // 2x32 KB [SWZ(n,k)]
    __shared__ unsigned short lxh[2][64 * 128];   // 2x16 KB
    __shared__ unsigned short lxl[2][64 * 128];   // 2x16 KB
    __shared__ float ls[NG2][128];                // 8 KB scales slice
    __shared__ float lz[NG2][128];                // 8 KB zeros slice
    __shared__ float lxs[NG2][64];                // 4 KB xsum slice

    const int tid = threadIdx.x;
    const int kh = blockIdx.x & (KSPLIT - 1);
    const int n0 = (blockIdx.x >> 2) * BN;
    const int g0 = kh * NG2;

    const int w = tid >> 6;
    const int l = tid & 63;
    const int lcol = l & 15;
    const int lhi = l >> 4;
    const int mt = (w >> 2) * 32;     // m-tile base: 0 or 32
    const int ns = (w & 3) * 32;      // n-strip base: 0,32,64,96

    const int qc = tid & 31;          // q staging: 16B col-chunk
    const int qr = tid >> 5;          // q staging: row octet
    const int xc = tid & 15;          // x staging: 8-elem chunk
    const int xm = tid >> 4;          // x staging: row

    const int c0 = n0 + ns + lcol;
    const int c1 = c0 + 16;

    int4v qva[8], qvb[8];             // 2-deep q register pipeline
    ushort8 xga, xgb, xgc, xgd;

    auto LOADX = [&](int g) {
        const size_t kb = (size_t)g * GRP + xc * 8;
        xga = *(const ushort8*)(xh + (size_t)xm * Kdim + kb);
        xgb = *(const ushort8*)(xh + (size_t)(xm + 32) * Kdim + kb);
        xgc = *(const ushort8*)(xl + (size_t)xm * Kdim + kb);
        xgd = *(const ushort8*)(xl + (size_t)(xm + 32) * Kdim + kb);
    };
    auto WRITEX = [&](int b) {
        *(ushort8*)&lxh[b][SWZ(xm, xc * 8)] = xga;
        *(ushort8*)&lxh[b][SWZ(xm + 32, xc * 8)] = xgb;
        *(ushort8*)&lxl[b][SWZ(xm, xc * 8)] = xgc;
        *(ushort8*)&lxl[b][SWZ(xm + 32, xc * 8)] = xgd;
    };

    f32x4 acc00 = {0,0,0,0}, acc01 = {0,0,0,0}, acc10 = {0,0,0,0}, acc11 = {0,0,0,0};

    auto COMPUTE = [&](int g) {       // lgkm-only phase; fold from LDS tables
        const int b = g & 1;
        f32x4 p00 = {0,0,0,0}, p01 = {0,0,0,0}, p10 = {0,0,0,0}, p11 = {0,0,0,0};
#pragma unroll
        for (int ks = 0; ks < 4; ++ks) {
            const int kk = ks * 32 + lhi * 8;
            short8 bq0 = *(const short8*)&lq[b][SWZ(ns + lcol, kk)];
            short8 bq1 = *(const short8*)&lq[b][SWZ(ns + 16 + lcol, kk)];
            short8 ah0 = *(const short8*)&lxh[b][SWZ(mt + lcol, kk)];
            short8 al0 = *(const short8*)&lxl[b][SWZ(mt + lcol, kk)];
            short8 ah1 = *(const short8*)&lxh[b][SWZ(mt + 16 + lcol, kk)];
            short8 al1 = *(const short8*)&lxl[b][SWZ(mt + 16 + lcol, kk)];
            p00 = __builtin_amdgcn_mfma_f32_16x16x32_bf16(ah0, bq0, p00, 0, 0, 0);
            p00 = __builtin_amdgcn_mfma_f32_16x16x32_bf16(al0, bq0, p00, 0, 0, 0);
            p01 = __builtin_amdgcn_mfma_f32_16x16x32_bf16(ah0, bq1, p01, 0, 0, 0);
            p01 = __builtin_amdgcn_mfma_f32_16x16x32_bf16(al0, bq1, p01, 0, 0, 0);
            p10 = __builtin_amdgcn_mfma_f32_16x16x32_bf16(ah1, bq0, p10, 0, 0, 0);
            p10 = __builtin_amdgcn_mfma_f32_16x16x32_bf16(al1, bq0, p10, 0, 0, 0);
            p11 = __builtin_amdgcn_mfma_f32_16x16x32_bf16(ah1, bq1, p11, 0, 0, 0);
            p11 = __builtin_amdgcn_mfma_f32_16x16x32_bf16(al1, bq1, p11, 0, 0, 0);
        }
        const float s0 = ls[g][ns + lcol],      z0 = lz[g][ns + lcol];
        const float s1 = ls[g][ns + 16 + lcol], z1 = lz[g][ns + 16 + lcol];
        f32x4 xs0 = *(const f32x4*)&lxs[g][mt + lhi * 4];
        f32x4 xs1 = *(const f32x4*)&lxs[g][mt + 16 + lhi * 4];
#pragma unroll
        for (int r = 0; r < 4; ++r) {
            acc00[r] += s0 * (p00[r] - z0 * xs0[r]);
            acc01[r] += s1 * (p01[r] - z1 * xs0[r]);
            acc10[r] += s0 * (p10[r] - z0 * xs1[r]);
            acc11[r] += s1 * (p11[r] - z1 * xs1[r]);
        }
    };

    // ---- prologue: tables + g0 staged (one full drain), then q(1)/q(2)/x(1) in flight
    {
        const int tg = tid >> 5, tc = tid & 31;
        f32x4 sv = *(const f32x4*)(scales + (size_t)(g0 + tg) * Ndim + n0 + tc * 4);
        f32x4 zv = *(const f32x4*)(zeros + (size_t)(g0 + tg) * Ndim + n0 + tc * 4);
        float x0 = xsum[(g0 + (tid >> 6)) * Mdim + (tid & 63)];
        float x1 = xsum[(g0 + ((tid + 512) >> 6)) * Mdim + (tid & 63)];
        LOADX(g0);
        LOADQ_M(qva, g0);             // q(0) -> set0
        *(f32x4*)&ls[tg][tc * 4] = sv;
        *(f32x4*)&lz[tg][tc * 4] = zv;
        (&lxs[0][0])[tid] = x0;
        (&lxs[0][0])[tid + 512] = x1;
        WRITEX(0);
        WRITEQ_M(qva, 0);             // full drain (once)
        LOADX(g0 + 1);
        LOADQ_M(qvb, g0 + 1);         // q(1) -> set1
        LOADQ_M(qva, g0 + 2);         // q(2) -> set0
        asm volatile("s_waitcnt lgkmcnt(0)" ::: "memory");
        __builtin_amdgcn_s_barrier();
    }

    // slot g: drains q(g+1) from set (g+1)&1, refills that set with q(g+3)
#define STEP(G, DSET) do {                                                    \
    const int g_ = (G);                                                       \
    COMPUTE(g_);                                                              \
    if (g_ + 1 < NG2) {                                                       \
        WRITEX((g_ & 1) ^ 1);                 /* waits x(g+1), counted */     \
        if (g_ + 2 < NG2) {                                                   \
            LOADX(g0 + g_ + 2);                                               \
            __builtin_amdgcn_sched_barrier(0);                                \
        }                                                                     \
        WRITEQ_M(DSET, (g_ & 1) ^ 1);         /* waits q(g+1), counted */     \
        if (g_ + 3 < NG2) {                                                   \
            LOADQ_M(DSET, g0 + g_ + 3);       /* 2-slot window refill */      \
            __builtin_amdgcn_sched_barrier(0);                                \
        }                                                                     \
        asm volatile("s_waitcnt lgkmcnt(0)" ::: "memory");                    \
        __builtin_amdgcn_s_barrier();                                         \
    }                                                                         \
} while (0)

    for (int gg = 0; gg < NG2; gg += 2) {
        STEP(gg, qvb);        // even slot drains set1 (q odd)
        STEP(gg + 1, qva);    // odd slot drains set0 (q even)
    }
#undef STEP

    // epilogue: accumulate into bias-initialized out (fp32 atomics)
#pragma unroll
    for (int r = 0; r < 4; ++r) {
        atomicAdd(out + (size_t)(mt + lhi * 4 + r) * Ndim + c0, acc00[r]);
        atomicAdd(out + (size_t)(mt + lhi * 4 + r) * Ndim + c1, acc01[r]);
        atomicAdd(out + (size_t)(mt + 16 + lhi * 4 + r) * Ndim + c0, acc10[r]);
        atomicAdd(out + (size_t)(mt + 16 + lhi * 4 + r) * Ndim + c1, acc11[r]);
    }
}

extern "C" void kernel_launch(void* const* d_in, const int* in_sizes, int n_in,
                              void* d_out, int out_size, void* d_ws, size_t ws_size,
                              hipStream_t stream) {
    const float* x = (const float*)d_in[0];
    const int* qw = (const int*)d_in[1];
    const float* scales = (const float*)d_in[2];
    const float* zeros = (const float*)d_in[3];
    const float* bias = (const float*)d_in[4];

    unsigned short* xh = (unsigned short*)d_ws;
    unsigned short* xl = xh + (size_t)Mdim * Kdim;
    float* xsum = (float*)(xl + (size_t)Mdim * Kdim);
    float* out = (float*)d_out;

    prep_kernel<<<512, 256, 0, stream>>>(x, xh, xl, xsum);
    init_kernel<<<(Mdim * Ndim / 4) / 256, 256, 0, stream>>>(bias, out);
    qlin_kernel<<<(Ndim / BN) * KSPLIT, 512, 0, stream>>>(xh, xl, qw, scales, zeros, xsum, out);
}

// Round 13
// 56.845 us; speedup vs baseline: 1.0250x; 1.0250x over previous
//
#include <hip/hip_runtime.h>

typedef __attribute__((ext_vector_type(8))) short short8;
typedef __attribute__((ext_vector_type(8))) unsigned short ushort8;
typedef __attribute__((ext_vector_type(4))) unsigned short ushort4v;
typedef __attribute__((ext_vector_type(4))) int int4v;
typedef __attribute__((ext_vector_type(4))) float f32x4;

#define Mdim 64
#define Kdim 8192
#define Ndim 8192
#define GRP 128
#define NGRP 64
#define KSPLIT 4
#define NG2 (NGRP / KSPLIT)   // 16 groups per block
#define BN 128

// Swizzled element offset in a [row][128]-bf16 LDS tile (256 B rows).
#define SWZ(row, kk) ((row)*128 + ((kk) ^ (8*((((row) >> 3) ^ (row)) & 7))))

__device__ __forceinline__ unsigned short f2bf(float f) {
    unsigned int u = __builtin_bit_cast(unsigned int, f);
    u += 0x7FFFu + ((u >> 16) & 1u);   // round-to-nearest-even
    return (unsigned short)(u >> 16);
}
__device__ __forceinline__ float bf2f(unsigned short h) {
    unsigned int u = ((unsigned int)h) << 16;
    return __builtin_bit_cast(float, u);
}

// Build xh/xl (hi/lo bf16 split of x) and per-(group,m) sums xsum[g][m].
__global__ void prep_kernel(const float* __restrict__ x,
                            unsigned short* __restrict__ xh,
                            unsigned short* __restrict__ xl,
                            float* __restrict__ xsum) {
    const int tid = threadIdx.x;
    const int u = blockIdx.x * 8 + (tid >> 5);
    const int g = u & (NGRP - 1);
    const int m = u >> 6;
    const int lane = tid & 31;
    const int k = g * GRP + lane * 4;
    f32x4 v = *(const f32x4*)(x + (size_t)m * Kdim + k);
    ushort4v hv, lv;
    float s = 0.f;
#pragma unroll
    for (int i = 0; i < 4; ++i) {
        unsigned short h = f2bf(v[i]);
        hv[i] = h;
        lv[i] = f2bf(v[i] - bf2f(h));
        s += v[i];
    }
    *(ushort4v*)(xh + (size_t)m * Kdim + k) = hv;
    *(ushort4v*)(xl + (size_t)m * Kdim + k) = lv;
#pragma unroll
    for (int off = 16; off > 0; off >>= 1) s += __shfl_down(s, off, 32);
    if (lane == 0) xsum[g * Mdim + m] = s;
}

// out = bias (broadcast over rows); qlin atomically accumulates into it.
__global__ void init_kernel(const float* __restrict__ bias,
                            float* __restrict__ out) {
    const size_t e = ((size_t)blockIdx.x * 256 + threadIdx.x) * 4;
    const int n = (int)(e & (Ndim - 1));
    *(f32x4*)(out + e) = *(const f32x4*)(bias + n);
}

// Main: 256 blocks = 64 n-tiles (BN=128) x KSPLIT=4, 1 block/CU (148 KB LDS).
// 512 threads = 8 waves = 2 m-tiles(32) x 4 n-strips(32).
// R11's proven k-loop: single q reg set, counted-vmcnt, RAW barriers
// (vmem survives). Per iter: compute(g) -> WRITEX(b^1)[waits x(g+1), q
// outstanding] -> LOADX(g+2) -> WRITEQ(b^1)[waits q(g+1); x(g+2) keeps HBM
// busy] -> LOADQ(g+2) -> lgkmcnt(0)+s_barrier.
// Epilogue: fp32 atomicAdd into bias-initialized out (no pout/reduce pass).
__launch_bounds__(512, 2)
__global__ void qlin_kernel(const unsigned short* __restrict__ xh,
                            const unsigned short* __restrict__ xl,
                            const int* __restrict__ qw,
                            const float* __restrict__ scales,
                            const float* __restrict__ zeros,
                            const float* __restrict__ xsum,
                            float* __restrict__ out) {
    __shared__ unsigned short lq[2][128 * 128];   // 2x32 KB [SWZ(n,k)]
    __shared__ unsigned short lxh[2][64 * 128];   // 2x16 KB
    __shared__ unsigned short lxl[2][64 * 128];   // 2x16 KB
    __shared__ float ls[NG2][128];                // 8 KB scales slice
    __shared__ float lz[NG2][128];                // 8 KB zeros slice
    __shared__ float lxs[NG2][64];                // 4 KB xsum slice

    const int tid = threadIdx.x;
    const int kh = blockIdx.x & (KSPLIT - 1);
    const int n0 = (blockIdx.x >> 2) * BN;
    const int g0 = kh * NG2;

    const int w = tid >> 6;
    const int l = tid & 63;
    const int lcol = l & 15;
    const int lhi = l >> 4;
    const int mt = (w >> 2) * 32;     // m-tile base: 0 or 32
    const int ns = (w & 3) * 32;      // n-strip base: 0,32,64,96

    const int qc = tid & 31;          // q staging: 16B col-chunk
    const int qr = tid >> 5;          // q staging: row octet
    const int xc = tid & 15;          // x staging: 8-elem chunk
    const int xm = tid >> 4;          // x staging: row

    const int c0 = n0 + ns + lcol;
    const int c1 = c0 + 16;

    int4v qv[8];
    ushort8 xga, xgb, xgc, xgd;

    auto LOADX = [&](int g) {
        const size_t kb = (size_t)g * GRP + xc * 8;
        xga = *(const ushort8*)(xh + (size_t)xm * Kdim + kb);
        xgb = *(const ushort8*)(xh + (size_t)(xm + 32) * Kdim + kb);
        xgc = *(const ushort8*)(xl + (size_t)xm * Kdim + kb);
        xgd = *(const ushort8*)(xl + (size_t)(xm + 32) * Kdim + kb);
    };
    auto LOADQ = [&](int g) {
        const size_t kb = (size_t)g * GRP + qr * 8;
        const int nc = n0 + qc * 4;
#pragma unroll
        for (int j = 0; j < 8; ++j)
            qv[j] = *(const int4v*)(qw + (kb + j) * Ndim + nc);
    };
    auto WRITEX = [&](int b) {
        *(ushort8*)&lxh[b][SWZ(xm, xc * 8)] = xga;
        *(ushort8*)&lxh[b][SWZ(xm + 32, xc * 8)] = xgb;
        *(ushort8*)&lxl[b][SWZ(xm, xc * 8)] = xgc;
        *(ushort8*)&lxl[b][SWZ(xm + 32, xc * 8)] = xgd;
    };
    auto WRITEQ = [&](int b) {        // exact int->bf16 (|q|<=128 => truncation exact)
#pragma unroll
        for (int i = 0; i < 4; ++i) {
            int4v pk;
#pragma unroll
            for (int t = 0; t < 4; ++t) {
                unsigned lo = __builtin_bit_cast(unsigned, (float)qv[2 * t][i]) >> 16;
                unsigned hi = __builtin_bit_cast(unsigned, (float)qv[2 * t + 1][i]) & 0xFFFF0000u;
                pk[t] = (int)(lo | hi);
            }
            *(int4v*)&lq[b][SWZ(qc * 4 + i, qr * 8)] = pk;
        }
    };

    f32x4 acc00 = {0,0,0,0}, acc01 = {0,0,0,0}, acc10 = {0,0,0,0}, acc11 = {0,0,0,0};

    // ---- prologue: tables + group g0 staged; q/x(g0+1) left IN FLIGHT ----
    {
        const int tg = tid >> 5, tc = tid & 31;
        f32x4 sv = *(const f32x4*)(scales + (size_t)(g0 + tg) * Ndim + n0 + tc * 4);
        f32x4 zv = *(const f32x4*)(zeros + (size_t)(g0 + tg) * Ndim + n0 + tc * 4);
        float x0 = xsum[(g0 + (tid >> 6)) * Mdim + (tid & 63)];
        float x1 = xsum[(g0 + ((tid + 512) >> 6)) * Mdim + (tid & 63)];
        LOADX(g0);
        LOADQ(g0);
        *(f32x4*)&ls[tg][tc * 4] = sv;
        *(f32x4*)&lz[tg][tc * 4] = zv;
        (&lxs[0][0])[tid] = x0;
        (&lxs[0][0])[tid + 512] = x1;
        WRITEX(0);
        WRITEQ(0);                    // drains q(g0)
        LOADX(g0 + 1);
        LOADQ(g0 + 1);
        asm volatile("s_waitcnt lgkmcnt(0)" ::: "memory");
        __builtin_amdgcn_s_barrier();
    }

    for (int g = 0; g < NG2; ++g) {
        const int b = g & 1;

        // compute phase: lgkm-only; x/q(g+1) arriving underneath
        f32x4 p00 = {0,0,0,0}, p01 = {0,0,0,0}, p10 = {0,0,0,0}, p11 = {0,0,0,0};
#pragma unroll
        for (int ks = 0; ks < 4; ++ks) {
            const int kk = ks * 32 + lhi * 8;
            short8 bq0 = *(const short8*)&lq[b][SWZ(ns + lcol, kk)];
            short8 bq1 = *(const short8*)&lq[b][SWZ(ns + 16 + lcol, kk)];
            short8 ah0 = *(const short8*)&lxh[b][SWZ(mt + lcol, kk)];
            short8 al0 = *(const short8*)&lxl[b][SWZ(mt + lcol, kk)];
            short8 ah1 = *(const short8*)&lxh[b][SWZ(mt + 16 + lcol, kk)];
            short8 al1 = *(const short8*)&lxl[b][SWZ(mt + 16 + lcol, kk)];
            p00 = __builtin_amdgcn_mfma_f32_16x16x32_bf16(ah0, bq0, p00, 0, 0, 0);
            p00 = __builtin_amdgcn_mfma_f32_16x16x32_bf16(al0, bq0, p00, 0, 0, 0);
            p01 = __builtin_amdgcn_mfma_f32_16x16x32_bf16(ah0, bq1, p01, 0, 0, 0);
            p01 = __builtin_amdgcn_mfma_f32_16x16x32_bf16(al0, bq1, p01, 0, 0, 0);
            p10 = __builtin_amdgcn_mfma_f32_16x16x32_bf16(ah1, bq0, p10, 0, 0, 0);
            p10 = __builtin_amdgcn_mfma_f32_16x16x32_bf16(al1, bq0, p10, 0, 0, 0);
            p11 = __builtin_amdgcn_mfma_f32_16x16x32_bf16(ah1, bq1, p11, 0, 0, 0);
            p11 = __builtin_amdgcn_mfma_f32_16x16x32_bf16(al1, bq1, p11, 0, 0, 0);
        }
        {   // group fold (LDS tables only)
            const float s0 = ls[g][ns + lcol],      z0 = lz[g][ns + lcol];
            const float s1 = ls[g][ns + 16 + lcol], z1 = lz[g][ns + 16 + lcol];
            f32x4 xs0 = *(const f32x4*)&lxs[g][mt + lhi * 4];
            f32x4 xs1 = *(const f32x4*)&lxs[g][mt + 16 + lhi * 4];
#pragma unroll
            for (int r = 0; r < 4; ++r) {
                acc00[r] += s0 * (p00[r] - z0 * xs0[r]);
                acc01[r] += s1 * (p01[r] - z1 * xs0[r]);
                acc10[r] += s0 * (p10[r] - z0 * xs1[r]);
                acc11[r] += s1 * (p11[r] - z1 * xs1[r]);
            }
        }

        if (g + 1 < NG2) {
            WRITEX(b ^ 1);                        // waits x(g+1); q(g+1) stays
            if (g + 2 < NG2) {
                LOADX(g0 + g + 2);                // outstanding during q drain
                __builtin_amdgcn_sched_barrier(0);
            }
            WRITEQ(b ^ 1);                        // waits q(g+1); x(g+2) in flight
            if (g + 2 < NG2) {
                LOADQ(g0 + g + 2);                // refill queue immediately
                __builtin_amdgcn_sched_barrier(0);
            }
            asm volatile("s_waitcnt lgkmcnt(0)" ::: "memory");
            __builtin_amdgcn_s_barrier();         // RAW: vmcnt survives
        }
    }

    // epilogue: accumulate into bias-initialized out (fp32 atomics, L2-side)
#pragma unroll
    for (int r = 0; r < 4; ++r) {
        atomicAdd(out + (size_t)(mt + lhi * 4 + r) * Ndim + c0, acc00[r]);
        atomicAdd(out + (size_t)(mt + lhi * 4 + r) * Ndim + c1, acc01[r]);
        atomicAdd(out + (size_t)(mt + 16 + lhi * 4 + r) * Ndim + c0, acc10[r]);
        atomicAdd(out + (size_t)(mt + 16 + lhi * 4 + r) * Ndim + c1, acc11[r]);
    }
}

extern "C" void kernel_launch(void* const* d_in, const int* in_sizes, int n_in,
                              void* d_out, int out_size, void* d_ws, size_t ws_size,
                              hipStream_t stream) {
    const float* x = (const float*)d_in[0];
    const int* qw = (const int*)d_in[1];
    const float* scales = (const float*)d_in[2];
    const float* zeros = (const float*)d_in[3];
    const float* bias = (const float*)d_in[4];

    unsigned short* xh = (unsigned short*)d_ws;
    unsigned short* xl = xh + (size_t)Mdim * Kdim;
    float* xsum = (float*)(xl + (size_t)Mdim * Kdim);
    float* out = (float*)d_out;

    prep_kernel<<<512, 256, 0, stream>>>(x, xh, xl, xsum);
    init_kernel<<<(Mdim * Ndim / 4) / 256, 256, 0, stream>>>(bias, out);
    qlin_kernel<<<(Ndim / BN) * KSPLIT, 512, 0, stream>>>(xh, xl, qw, scales, zeros, xsum, out);
}